// Round 1
// baseline (74.299 us; speedup 1.0000x reference)
//
#include <hip/hip_runtime.h>
#include <math.h>

// VanillaSFNN: B=1024, T=1024, H=256, IN=2, OUT=2, DECAY=0.8
// out[b,o] = sum_t 0.8^(T-1-t) * (spikes[b,t,:] @ W_out[o,:]) + b_out[o]*sum_k 0.8^k
// Strategy: 1 block per batch element, 1 thread per hidden unit.
//   - stage x[b] (2048 f32 = 8KB) in LDS, broadcast-read per timestep
//   - each thread runs the sequential LIF recurrence over T, accumulating a
//     decayed spike sum S (output side is linear in spikes -> project once)
//   - v-path arithmetic mimics the reference f32 op order (no FMA) to avoid
//     spike flips vs the numpy reference.

constexpr int T_STEPS = 1024;
constexpr int HIDDEN  = 256;

__global__ __launch_bounds__(256) void sfnn_kernel(
    const float* __restrict__ x_seq,   // [B, T, 2]
    const float* __restrict__ W_in,    // [H, 2]
    const float* __restrict__ b_in,    // [H]
    const float* __restrict__ W_out,   // [2, H]
    const float* __restrict__ b_out,   // [2]
    const float* __restrict__ tau_m,   // [H]
    float* __restrict__ out)           // [B, 2]
{
    __shared__ float4 xs[T_STEPS / 2];     // 512 float4 = 8 KB: x[b] staged
    __shared__ float red0[HIDDEN];
    __shared__ float red1[HIDDEN];

    const int b = blockIdx.x;
    const int h = threadIdx.x;

    // --- stage x[b] into LDS (coalesced: 2 float4 per thread) ---
    const float4* __restrict__ xg =
        reinterpret_cast<const float4*>(x_seq) + (size_t)b * (T_STEPS / 2);
    xs[h]           = xg[h];
    xs[h + HIDDEN]  = xg[h + HIDDEN];

    // --- per-hidden constants ---
    const float w0    = W_in[2 * h];
    const float w1    = W_in[2 * h + 1];
    const float bi    = b_in[h];
    const float alpha = 1.0f / (1.0f + expf(-tau_m[h]));   // sigmoid, accurate exp
    const float beta  = 1.0f - alpha;                       // exact (alpha in (0.5,1))

    __syncthreads();

    float v = 0.0f;
    float S = 0.0f;   // decayed spike accumulator: S = 0.8*S + spike

    #pragma unroll 4
    for (int i = 0; i < T_STEPS / 2; ++i) {
        const float4 x2 = xs[i];   // timesteps 2i (x,y) and 2i+1 (z,w); LDS broadcast

        // t = 2i
        {
            float cur = __fadd_rn(__fadd_rn(__fmul_rn(x2.x, w0), __fmul_rn(x2.y, w1)), bi);
            v = __fadd_rn(__fmul_rn(v, alpha), __fmul_rn(beta, cur));
            float sp = (v >= 1.0f) ? 1.0f : 0.0f;
            v -= sp;
            S = fmaf(0.8f, S, sp);
        }
        // t = 2i+1
        {
            float cur = __fadd_rn(__fadd_rn(__fmul_rn(x2.z, w0), __fmul_rn(x2.w, w1)), bi);
            v = __fadd_rn(__fmul_rn(v, alpha), __fmul_rn(beta, cur));
            float sp = (v >= 1.0f) ? 1.0f : 0.0f;
            v -= sp;
            S = fmaf(0.8f, S, sp);
        }
    }

    // --- project S onto W_out and block-reduce over h ---
    red0[h] = S * W_out[h];            // W_out[0][h]
    red1[h] = S * W_out[HIDDEN + h];   // W_out[1][h]
    __syncthreads();

    #pragma unroll
    for (int s = HIDDEN / 2; s > 0; s >>= 1) {
        if (h < s) {
            red0[h] += red0[h + s];
            red1[h] += red1[h + s];
        }
        __syncthreads();
    }

    if (h == 0) {
        // b_out coefficient: sum_{k=0}^{T-1} 0.8^k = 5*(1 - 0.8^1024) == 5.0f in f32
        const float geo = 5.0f;
        out[2 * b]     = red0[0] + b_out[0] * geo;
        out[2 * b + 1] = red1[0] + b_out[1] * geo;
    }
}

extern "C" void kernel_launch(void* const* d_in, const int* in_sizes, int n_in,
                              void* d_out, int out_size, void* d_ws, size_t ws_size,
                              hipStream_t stream) {
    const float* x_seq = (const float*)d_in[0];
    const float* W_in  = (const float*)d_in[1];
    const float* b_in  = (const float*)d_in[2];
    const float* W_out = (const float*)d_in[3];
    const float* b_out = (const float*)d_in[4];
    const float* tau_m = (const float*)d_in[5];
    float* out = (float*)d_out;

    sfnn_kernel<<<dim3(1024), dim3(256), 0, stream>>>(
        x_seq, W_in, b_in, W_out, b_out, tau_m, out);
}

// Round 2
// 69.957 us; speedup vs baseline: 1.0621x; 1.0621x over previous
//
#include <hip/hip_runtime.h>
#include <math.h>

// VanillaSFNN: B=1024, T=1024, H=256, IN=2, OUT=2, DECAY=0.8
// Round 2: packed-FP32 (v_pk_*_f32) version — 2 hidden units per lane.
//   - grid 1024 (1 block per batch), block 128; lane handles h and h+128
//   - x[b] staged in LDS duplicated per step: {x0,x0,x1,x1} (16 KB)
//     -> one ds_read_b128 per timestep gives both packed operands directly
//   - all recurrence arithmetic in VOP3P packed f32 (bit-exact per half vs
//     scalar mul/add order of the reference; spike decisions unchanged)
//   - spikes accumulated NEGATED (spn in {-1,0}) so reset + S-update stay
//     packed; sign-symmetric fma is bit-identical to fmaf(0.8,S,sp)

constexpr int T_STEPS = 1024;
constexpr int HIDDEN  = 256;
constexpr int BLK     = 128;   // threads per block; lane covers h, h+128

typedef float f32x2 __attribute__((ext_vector_type(2)));
typedef float f32x4 __attribute__((ext_vector_type(4)));

__device__ __forceinline__ f32x2 pk_mul(f32x2 a, f32x2 b) {
    f32x2 d; asm("v_pk_mul_f32 %0, %1, %2" : "=v"(d) : "v"(a), "v"(b)); return d;
}
__device__ __forceinline__ f32x2 pk_add(f32x2 a, f32x2 b) {
    f32x2 d; asm("v_pk_add_f32 %0, %1, %2" : "=v"(d) : "v"(a), "v"(b)); return d;
}
__device__ __forceinline__ f32x2 pk_fma(f32x2 a, f32x2 b, f32x2 c) {
    f32x2 d; asm("v_pk_fma_f32 %0, %1, %2, %3" : "=v"(d) : "v"(a), "v"(b), "v"(c)); return d;
}

__global__ __launch_bounds__(BLK) void sfnn_pk_kernel(
    const float* __restrict__ x_seq,   // [B, T, 2]
    const float* __restrict__ W_in,    // [H, 2]
    const float* __restrict__ b_in,    // [H]
    const float* __restrict__ W_out,   // [2, H]
    const float* __restrict__ b_out,   // [2]
    const float* __restrict__ tau_m,   // [H]
    float* __restrict__ out)           // [B, 2]
{
    __shared__ f32x4 xs[T_STEPS];      // 16 KB: per step {x0,x0,x1,x1}
    __shared__ float red0[BLK];
    __shared__ float red1[BLK];

    const int b   = blockIdx.x;
    const int tid = threadIdx.x;
    const int h0  = tid;
    const int h1  = tid + BLK;

    // --- stage x[b] into LDS, duplicating each component ---
    // input: 512 float4 (each covers 2 timesteps); output: 1024 f32x4
    const float4* __restrict__ xg =
        reinterpret_cast<const float4*>(x_seq) + (size_t)b * (T_STEPS / 2);
    #pragma unroll
    for (int k = 0; k < 4; ++k) {
        const int j = tid + k * BLK;          // input float4 index, 0..511
        const float4 in4 = xg[j];
        f32x4 a; a.x = in4.x; a.y = in4.x; a.z = in4.y; a.w = in4.y;
        f32x4 c; c.x = in4.z; c.y = in4.z; c.z = in4.w; c.w = in4.w;
        xs[2 * j]     = a;                    // timestep 2j
        xs[2 * j + 1] = c;                    // timestep 2j+1
    }

    // --- per-lane packed constants (two hidden units) ---
    f32x2 w0p, w1p, bip, alphap, betap;
    w0p.x = W_in[2 * h0];     w0p.y = W_in[2 * h1];
    w1p.x = W_in[2 * h0 + 1]; w1p.y = W_in[2 * h1 + 1];
    bip.x = b_in[h0];         bip.y = b_in[h1];
    alphap.x = 1.0f / (1.0f + expf(-tau_m[h0]));
    alphap.y = 1.0f / (1.0f + expf(-tau_m[h1]));
    betap.x  = 1.0f - alphap.x;
    betap.y  = 1.0f - alphap.y;
    f32x2 c08; c08.x = 0.8f; c08.y = 0.8f;

    __syncthreads();

    f32x2 v;  v.x = 0.0f;  v.y = 0.0f;
    f32x2 Sn; Sn.x = 0.0f; Sn.y = 0.0f;   // negated decayed spike sum

    #pragma unroll 4
    for (int t = 0; t < T_STEPS; ++t) {
        const f32x4 xq = xs[t];            // {x0,x0,x1,x1} — LDS broadcast
        f32x2 x0p; x0p.x = xq.x; x0p.y = xq.y;
        f32x2 x1p; x1p.x = xq.z; x1p.y = xq.w;

        // cur = (x0*w0 + x1*w1) + b_in   (exact reference op order, per half)
        f32x2 t0  = pk_mul(x0p, w0p);
        f32x2 t1  = pk_mul(x1p, w1p);
        f32x2 cur = pk_add(pk_add(t0, t1), bip);

        // v = v*alpha + (1-alpha)*cur    (exact reference op order, per half)
        v = pk_add(pk_mul(v, alphap), pk_mul(betap, cur));

        // spike (negated): spn = (v >= 1) ? -1 : 0
        f32x2 spn;
        spn.x = (v.x >= 1.0f) ? -1.0f : 0.0f;
        spn.y = (v.y >= 1.0f) ? -1.0f : 0.0f;

        v  = pk_add(v, spn);               // soft reset: v -= spike
        Sn = pk_fma(c08, Sn, spn);         // Sn = 0.8*Sn - spike
    }

    // --- project (-Sn) onto W_out and block-reduce over 128 lanes ---
    const float Sx = -Sn.x, Sy = -Sn.y;
    red0[tid] = fmaf(Sy, W_out[h1],          Sx * W_out[h0]);
    red1[tid] = fmaf(Sy, W_out[HIDDEN + h1], Sx * W_out[HIDDEN + h0]);
    __syncthreads();

    #pragma unroll
    for (int s = BLK / 2; s > 0; s >>= 1) {
        if (tid < s) {
            red0[tid] += red0[tid + s];
            red1[tid] += red1[tid + s];
        }
        __syncthreads();
    }

    if (tid == 0) {
        const float geo = 5.0f;   // sum_{k=0}^{1023} 0.8^k rounds to 5.0f
        out[2 * b]     = red0[0] + b_out[0] * geo;
        out[2 * b + 1] = red1[0] + b_out[1] * geo;
    }
}

extern "C" void kernel_launch(void* const* d_in, const int* in_sizes, int n_in,
                              void* d_out, int out_size, void* d_ws, size_t ws_size,
                              hipStream_t stream) {
    const float* x_seq = (const float*)d_in[0];
    const float* W_in  = (const float*)d_in[1];
    const float* b_in  = (const float*)d_in[2];
    const float* W_out = (const float*)d_in[3];
    const float* b_out = (const float*)d_in[4];
    const float* tau_m = (const float*)d_in[5];
    float* out = (float*)d_out;

    sfnn_pk_kernel<<<dim3(1024), dim3(BLK), 0, stream>>>(
        x_seq, W_in, b_in, W_out, b_out, tau_m, out);
}